// Round 14
// baseline (213.419 us; speedup 1.0000x reference)
//
#include <hip/hip_runtime.h>
#include <stdint.h>
#include <stddef.h>

// Problem constants
#define B_ 4
#define L_ 8192
#define D_ 512
#define M_ (B_*L_)      // 32768 rows
#define K_ 512
#define CHUNK 64
#define NC (L_/CHUNK)   // 128 chunks per sequence

typedef _Float16 f16;
typedef f16 f16x2 __attribute__((ext_vector_type(2)));
typedef f16 f16x8 __attribute__((ext_vector_type(8)));
typedef float f32x4 __attribute__((ext_vector_type(4)));

// ---------------- async global->LDS (16B/lane) ----------------
__device__ __forceinline__ void async16(const void* g, void* l) {
  __builtin_amdgcn_global_load_lds(
      (const __attribute__((address_space(1))) uint32_t*)g,
      (__attribute__((address_space(3))) uint32_t*)l,
      16, 0, 0);
}

// ---------------- prep: cvt x -> f16 and pack Wg++Wc, LINEAR layout -------
// 8 floats/thread: 32B read, 16B write. Verified R13.
__global__ __launch_bounds__(256) void prep(const float* __restrict__ x,
                                            const float* __restrict__ Wg,
                                            const float* __restrict__ Wc,
                                            f16* __restrict__ xh,
                                            f16* __restrict__ wp) {
  const int bid = blockIdx.x;
  const int isX = (bid < 8192);
  const int U = (isX ? bid : (bid - 8192)) * 256 + threadIdx.x;  // unit idx
  const float* src;
  f16* dst;
  if (isX)            { src = x + (size_t)U * 8;                     dst = xh; }
  else if (U < 32768) { src = Wg + (size_t)U * 8;                    dst = wp; }
  else                { src = Wc + (size_t)(U - 32768) * 8;          dst = wp; }
  float4 v0 = *(const float4*)src;
  float4 v1 = *(const float4*)(src + 4);
  f16x8 o = {(f16)v0.x, (f16)v0.y, (f16)v0.z, (f16)v0.w,
             (f16)v1.x, (f16)v1.y, (f16)v1.z, (f16)v1.w};
  *(f16x8*)(dst + (size_t)U * 8) = o;
}

// ---------------- fused dual-B GEMM + activations + chunk composites ------
// v14 = R5's verified 256x128/512-thr/BK=32 structure + the ONE untested
// lever: TRIPLE-buffered LDS (96KB, free: occupancy is reg-capped at
// 2 waves/SIMD) with counted vmcnt(4) — 2 K-tiles in flight, so each
// step's wait covers only the PREVIOUS step's loads (fully latency-hidden)
// and the newest 4 loads cross the barrier in flight (T3/T4 recipe).
// Hazards: buf[(t+2)%3] written at t was last read at t-1 (ds_reads retired
// before t-1's MFMAs -> before its barrier). Tile t+1's DMA lands in a
// buffer nobody reads until after the next wait+barrier.
__global__ __launch_bounds__(512, 2) void gemm_act(
    const f16* __restrict__ Xh, const f16* __restrict__ Wp,
    const float* __restrict__ bg, const float* __restrict__ bc,
    uint32_t* __restrict__ AC,
    float* __restrict__ cA, float* __restrict__ cB) {
  __shared__ __align__(16) f16 sA[3][256 * 32];    // 3 x 16 KB
  __shared__ __align__(16) f16 sBg[3][128 * 32];   // 3 x 8 KB
  __shared__ __align__(16) f16 sBc[3][128 * 32];   // 3 x 8 KB => 96 KB

  const int tid = threadIdx.x;
  // XCD swizzle: contiguous range per XCD (512 = 8 * 64, bijective)
  const int id = blockIdx.x;           // 0..511
  const int xcd = id & 7;
  const int slot = id >> 3;            // 0..63
  const int g_ = xcd * 64 + slot;
  const int bm = g_ >> 2;              // 0..127 (256-row tiles)
  const int bn = g_ & 3;               // 0..3 (128-col tiles)

  const int lane = tid & 63;
  const int w = tid >> 6;              // 0..7
  const int wm = w >> 1, wn = w & 1;   // 4x2 wave grid over 256x128
  const int l15 = lane & 15, quad = lane >> 4;

  // staging: tid -> (row = tid>>2, 16B piece = tid&3); covers 128 rows/inst
  const int srow = tid >> 2;           // 0..127
  const int spc8 = (tid & 3) * 8;
  const f16* gA  = Xh + (size_t)(bm * 256 + srow) * K_ + spc8;
  const f16* gBg = Wp + (size_t)(bn * 128 + srow) * K_ + spc8;
  const f16* gBc = Wp + (size_t)(512 + bn * 128 + srow) * K_ + spc8;

  f32x4 accG[4][4] = {};
  f32x4 accC[4][4] = {};

#define STAGE(kk, b) { \
    async16(gA + (kk),  &sA[b][tid * 8]); \
    async16(gA + (size_t)128 * K_ + (kk), &sA[b][tid * 8 + 128 * 32]); \
    async16(gBg + (kk), &sBg[b][tid * 8]); \
    async16(gBc + (kk), &sBc[b][tid * 8]); }

#define COMPUTE(bC) { \
    f16x8 af[4], bgf[4], bcf[4]; \
    _Pragma("unroll") \
    for (int i = 0; i < 4; i++) \
      af[i] = *(const f16x8*)(&sA[bC][(wm * 64 + i * 16 + l15) * 32 + quad * 8]); \
    _Pragma("unroll") \
    for (int j = 0; j < 4; j++) { \
      bgf[j] = *(const f16x8*)(&sBg[bC][(wn * 64 + j * 16 + l15) * 32 + quad * 8]); \
      bcf[j] = *(const f16x8*)(&sBc[bC][(wn * 64 + j * 16 + l15) * 32 + quad * 8]); \
    } \
    _Pragma("unroll") \
    for (int i = 0; i < 4; i++) \
      _Pragma("unroll") \
      for (int j = 0; j < 4; j++) { \
        accG[i][j] = __builtin_amdgcn_mfma_f32_16x16x32_f16(af[i], bgf[j], accG[i][j], 0, 0, 0); \
        accC[i][j] = __builtin_amdgcn_mfma_f32_16x16x32_f16(af[i], bcf[j], accC[i][j], 0, 0, 0); \
      } }

  // Prologue: tiles 0 and 1 in flight; wait only tile 0 (oldest 4 of 8).
  STAGE(0, 0);
  STAGE(32, 1);
  asm volatile("s_waitcnt vmcnt(4)" ::: "memory");
  __builtin_amdgcn_s_barrier();

  // Steady state: stage t+2, compute t, wait tile t+1 only (vmcnt(4):
  // the 4 newest loads — tile t+2 — stay in flight across the barrier).
#pragma unroll
  for (int t = 0; t < 16; t++) {
    if (t + 2 < 16) STAGE((t + 2) * 32, (t + 2) % 3);
    COMPUTE(t % 3);
    if (t < 15) {
      if (t + 2 < 16) { asm volatile("s_waitcnt vmcnt(4)" ::: "memory"); }
      else            { asm volatile("s_waitcnt vmcnt(0)" ::: "memory"); }
      __builtin_amdgcn_s_barrier();
    }
  }
#undef COMPUTE
#undef STAGE

  // Epilogue: sigmoid/tanh, pack (a,b) f16x2 -> AC, and per-chunk (P,Q).
  // Wave wm owns rows [wm*64, wm*64+64) of the 256-row tile = chunk
  // c = bm*4 + wm. Within chunk, t = i*16 + quad*4 + r. (Verified R5.)
  const int c = bm * 4 + wm;           // global chunk index 0..511
#pragma unroll
  for (int j = 0; j < 4; j++) {
    const int col = bn * 128 + wn * 64 + j * 16 + l15;   // 0..511
    const float bgv = bg[col];
    const float bcv = bc[col];
    float blkP[4], blkQ[4];
#pragma unroll
    for (int i = 0; i < 4; i++) {
      const int mrow = bm * 256 + wm * 64 + i * 16 + quad * 4;
      float P = 1.0f, Q = 0.0f;
#pragma unroll
      for (int r = 0; r < 4; r++) {
        float yg = accG[i][j][r] + bgv;
        float gg = 1.0f / (1.0f + __expf(-yg));        // sigmoid
        float yc = accC[i][j][r] + bcv;
        yc = fminf(fmaxf(yc, -15.0f), 15.0f);
        float t = __expf(2.0f * yc);
        float cc = (t - 1.0f) / (t + 1.0f);            // tanh
        f16x2 p;
        p[0] = (f16)(1.0f - gg);                        // a
        p[1] = (f16)(gg * cc);                          // b
        *(f16x2*)&AC[(size_t)(mrow + r) * 512 + col] = p;
        // compose with the SAME f16-rounded values scan_apply will read
        const float av = (float)p[0];
        const float bv = (float)p[1];
        Q = fmaf(av, Q, bv);                            // seg over r (t asc)
        P *= av;
      }
      // ordered cross-quad compose: quads 0..3 are consecutive t-segments.
      float Pp = __shfl_xor(P, 16);
      float Qp = __shfl_xor(Q, 16);
      float nP = P * Pp;
      float nQ = (quad & 1) ? fmaf(P, Qp, Q) : fmaf(Pp, Q, Qp);
      Pp = __shfl_xor(nP, 32);
      Qp = __shfl_xor(nQ, 32);
      blkP[i] = nP * Pp;
      blkQ[i] = (quad & 2) ? fmaf(nP, Qp, nQ) : fmaf(Pp, nQ, Qp);
    }
    // compose the 4 sixteen-row blocks in t order
    float CP = blkP[0], CQ = blkQ[0];
#pragma unroll
    for (int i = 1; i < 4; i++) {
      CQ = fmaf(blkP[i], CQ, blkQ[i]);
      CP *= blkP[i];
    }
    if (quad == 0) {
      cA[(size_t)c * 512 + col] = CP;
      cB[(size_t)c * 512 + col] = CQ;
    }
  }
}

// ---------------- scan: inline chunk-prefix + apply, 16B/lane -------------
// R5's verified merged version (best-measured total). Each block = one
// chunk; thread owns 4 cols (float4 = peak-BW width). Prefix over chunks
// 0..ch-1 from L2-resident cA/cB, then the 64-step recurrence.
__global__ __launch_bounds__(128) void scan_apply(
    const uint32_t* __restrict__ AC,
    const float* __restrict__ cA, const float* __restrict__ cB,
    float* __restrict__ out) {
  const int blk = blockIdx.x;          // 0..511 = b*NC + ch
  const int ch = blk & (NC - 1);
  const int bseq = blk >> 7;           // NC = 128
  const int d0 = threadIdx.x * 4;      // 128 thr x 4 cols = 512

  float h0 = 0.0f, h1 = 0.0f, h2 = 0.0f, h3 = 0.0f;
  const float* pA = cA + (size_t)(bseq * NC) * 512 + d0;
  const float* pB = cB + (size_t)(bseq * NC) * 512 + d0;
#pragma unroll 4
  for (int cc = 0; cc < ch; cc++) {
    float4 va = *(const float4*)(pA + (size_t)cc * 512);
    float4 vb = *(const float4*)(pB + (size_t)cc * 512);
    h0 = fmaf(va.x, h0, vb.x);
    h1 = fmaf(va.y, h1, vb.y);
    h2 = fmaf(va.z, h2, vb.z);
    h3 = fmaf(va.w, h3, vb.w);
  }

  const size_t base = (size_t)blk * CHUNK * 512 + d0;
#pragma unroll 8
  for (int t = 0; t < CHUNK; t++) {
    const size_t i = base + (size_t)t * 512;
    uint4 v = *(const uint4*)&AC[i];
    f16x2 p0 = __builtin_bit_cast(f16x2, v.x);
    f16x2 p1 = __builtin_bit_cast(f16x2, v.y);
    f16x2 p2 = __builtin_bit_cast(f16x2, v.z);
    f16x2 p3 = __builtin_bit_cast(f16x2, v.w);
    h0 = fmaf((float)p0[0], h0, (float)p0[1]);
    h1 = fmaf((float)p1[0], h1, (float)p1[1]);
    h2 = fmaf((float)p2[0], h2, (float)p2[1]);
    h3 = fmaf((float)p3[0], h3, (float)p3[1]);
    float4 o;
    o.x = h0; o.y = h1; o.z = h2; o.w = h3;
    *(float4*)&out[i] = o;
  }
}

// ---------------- launch ----------------
extern "C" void kernel_launch(void* const* d_in, const int* in_sizes, int n_in,
                              void* d_out, int out_size, void* d_ws, size_t ws_size,
                              hipStream_t stream) {
  const float* x  = (const float*)d_in[0];
  const float* Wg = (const float*)d_in[1];
  const float* bg = (const float*)d_in[2];
  const float* Wc = (const float*)d_in[3];
  const float* bc = (const float*)d_in[4];
  float* out = (float*)d_out;

  char* ws = (char*)d_ws;
  // workspace layout (bytes):
  //   [0, 32MB)      xh   f16 x
  //   [32MB, 33MB)   wp   f16 packed weights [1024][512]
  //   [33MB, 97MB)   AC   u32 packed (a,b) f16x2 [32768][512]
  //   [97MB..99MB)   cA, cB fp32 (1MB each)
  f16*      xh = (f16*)(ws);
  f16*      wp = (f16*)(ws + 33554432);
  uint32_t* AC = (uint32_t*)(ws + 34603008);
  float*    cA = (float*)(ws + 101711872);
  float*    cB = (float*)(ws + 102760448);

  prep<<<8448, 256, 0, stream>>>(x, Wg, Wc, xh, wp);
  gemm_act<<<512, 512, 0, stream>>>(xh, wp, bg, bc, AC, cA, cB);  // 256x128, 3-buf
  scan_apply<<<B_ * NC, 128, 0, stream>>>(AC, cA, cB, out);
}